// Round 3
// baseline (257.491 us; speedup 1.0000x reference)
//
#include <hip/hip_runtime.h>
#include <math.h>

#define BB 16
#define HH 256
#define WW 256
#define PW 258

// ws layout in floats
#define OFF_CHSUM 0      // [64]
#define OFF_CHSQ  64     // [64]
#define OFF_A     128    // [64]  rsig * bn_w
#define OFF_B     192    // [64]  bn_b - mu * A
#define OFF_FEAT  256    // [16*64] pooled relu sums (pre-division)
#define OFF_SRF   1280   // [16*3*31]
#define SRF_N     (16 * 93)
#define OFF_X4    4096   // padded input: 16 x 258 x 258 x float4
#define X4_FLOATS (16 * PW * PW * 4)
#define WS_NEED_BYTES ((size_t)(OFF_X4 + X4_FLOATS) * 4)

__global__ void k_init(float* __restrict__ ws) {
    int i = blockIdx.x * 256 + threadIdx.x;
    if (i < 1280) ws[i] = 0.f;
}

// ---------------- padded-layout fast path ----------------

__global__ __launch_bounds__(256) void k_pad(const float* __restrict__ x,
                                             float* __restrict__ ws) {
    int b = blockIdx.y;
    int i = blockIdx.x * 256 + threadIdx.x;
    if (i >= PW * PW) return;
    int pr = i / PW, pc = i % PW;
    float4 v = make_float4(0.f, 0.f, 0.f, 0.f);
    if (pr >= 1 && pr <= HH && pc >= 1 && pc <= WW) {
        const float* p = x + (((size_t)b * HH + (pr - 1)) * WW + (pc - 1)) * 3;
        v.x = p[0]; v.y = p[1]; v.z = p[2];
    }
    ((float4*)(ws + OFF_X4))[((size_t)b * PW + pr) * PW + pc] = v;
}

// MODE 0: per-channel sum/sumsq.  MODE 1: BN+ReLU, per-(b,c) pool sum.
// 5-row register rotation; loads issued 2 pixels ahead of consumption.
template <int MODE>
__global__ __launch_bounds__(256) void k_convp(const float* __restrict__ cw,
                                               const float* __restrict__ cb,
                                               float* __restrict__ ws) {
    const int lane = threadIdx.x & 63;   // output channel
    const int wv   = threadIdx.x >> 6;
    const int b    = blockIdx.y;
    const int col  = blockIdx.x * 4 + wv;   // output col 0..255
    const int r0   = blockIdx.z * 128;      // output row base

    float wt[27];
#pragma unroll
    for (int k = 0; k < 27; ++k) wt[k] = cw[lane * 27 + k];
    const float bias = cb[lane];
    float A = 0.f, Bc = 0.f;
    if (MODE == 1) { A = ws[OFF_A + lane]; Bc = ws[OFF_B + lane]; }

    const float4* rp = (const float4*)(ws + OFF_X4) + ((size_t)(b * PW + r0)) * PW + col;

    float4 R0[3], R1[3], R2[3], R3[3], R4[3];
#define LD(R) { R[0] = rp[0]; R[1] = rp[1]; R[2] = rp[2]; rp += PW; }
    LD(R0) LD(R1) LD(R2) LD(R3)   // padded rows r0+0 .. r0+3

    float acc_s = 0.f, acc_q = 0.f;

#define PX(RA, RB, RC)                                                        \
    {                                                                         \
        float y0 = bias, y1 = 0.f, y2 = 0.f;                                  \
        y0 = fmaf(wt[0], RA[0].x, y0); y0 = fmaf(wt[1], RA[1].x, y0);         \
        y0 = fmaf(wt[2], RA[2].x, y0); y0 = fmaf(wt[3], RB[0].x, y0);         \
        y0 = fmaf(wt[4], RB[1].x, y0); y0 = fmaf(wt[5], RB[2].x, y0);         \
        y0 = fmaf(wt[6], RC[0].x, y0); y0 = fmaf(wt[7], RC[1].x, y0);         \
        y0 = fmaf(wt[8], RC[2].x, y0);                                        \
        y1 = fmaf(wt[9], RA[0].y, y1); y1 = fmaf(wt[10], RA[1].y, y1);        \
        y1 = fmaf(wt[11], RA[2].y, y1); y1 = fmaf(wt[12], RB[0].y, y1);       \
        y1 = fmaf(wt[13], RB[1].y, y1); y1 = fmaf(wt[14], RB[2].y, y1);       \
        y1 = fmaf(wt[15], RC[0].y, y1); y1 = fmaf(wt[16], RC[1].y, y1);       \
        y1 = fmaf(wt[17], RC[2].y, y1);                                       \
        y2 = fmaf(wt[18], RA[0].z, y2); y2 = fmaf(wt[19], RA[1].z, y2);       \
        y2 = fmaf(wt[20], RA[2].z, y2); y2 = fmaf(wt[21], RB[0].z, y2);       \
        y2 = fmaf(wt[22], RB[1].z, y2); y2 = fmaf(wt[23], RB[2].z, y2);       \
        y2 = fmaf(wt[24], RC[0].z, y2); y2 = fmaf(wt[25], RC[1].z, y2);       \
        y2 = fmaf(wt[26], RC[2].z, y2);                                       \
        float y = (y0 + y1) + y2;                                             \
        if (MODE == 0) {                                                      \
            acc_s += y;                                                       \
            acc_q = fmaf(y, y, acc_q);                                        \
        } else {                                                              \
            float t = fmaxf(fmaf(y, A, Bc), 0.f);                             \
            acc_s += t;                                                       \
        }                                                                     \
    }

    // pixels 0..124: 5-phase rotation, each load lands 2 pixels before use
#pragma unroll 1
    for (int i = 0; i < 25; ++i) {
        PX(R0, R1, R2) LD(R4)
        PX(R1, R2, R3) LD(R0)
        PX(R2, R3, R4) LD(R1)
        PX(R3, R4, R0) LD(R2)
        PX(R4, R0, R1) LD(R3)
    }
    // after loop: R0=row125, R1=126, R2=127, R3=128 (mod padded-row indices)
    PX(R0, R1, R2) LD(R4)   // loads padded row r0+129 (max 257: in bounds)
    PX(R1, R2, R3)
    PX(R2, R3, R4)
#undef PX
#undef LD

    __shared__ float red[4][64][2];
    red[wv][lane][0] = acc_s;
    if (MODE == 0) red[wv][lane][1] = acc_q;
    __syncthreads();
    if (wv == 0) {
        float S = red[0][lane][0] + red[1][lane][0] + red[2][lane][0] + red[3][lane][0];
        if (MODE == 0) {
            float Q = red[0][lane][1] + red[1][lane][1] + red[2][lane][1] + red[3][lane][1];
            atomicAdd(&ws[OFF_CHSUM + lane], S);
            atomicAdd(&ws[OFF_CHSQ + lane], Q);
        } else {
            atomicAdd(&ws[OFF_FEAT + b * 64 + lane], S);
        }
    }
}

// ---------------- fallback (round-1) conv, used only if ws too small ----------------

__device__ __forceinline__ void loadrow(const float* __restrict__ xb, int rr, int col,
                                        float* dst) {
    if (rr < 0 || rr >= HH) {
#pragma unroll
        for (int k = 0; k < 9; ++k) dst[k] = 0.f;
        return;
    }
    const float* p = xb + rr * (WW * 3);
#pragma unroll
    for (int kw = 0; kw < 3; ++kw) {
        int cc = col - 1 + kw;
        if (cc >= 0 && cc < WW) {
            dst[kw * 3 + 0] = p[cc * 3 + 0];
            dst[kw * 3 + 1] = p[cc * 3 + 1];
            dst[kw * 3 + 2] = p[cc * 3 + 2];
        } else {
            dst[kw * 3 + 0] = 0.f; dst[kw * 3 + 1] = 0.f; dst[kw * 3 + 2] = 0.f;
        }
    }
}

__device__ __forceinline__ float dorow(const float* wt, float bias,
                                       const float* r0, const float* r1, const float* r2) {
    float y = bias;
#pragma unroll
    for (int ci = 0; ci < 3; ++ci) {
#pragma unroll
        for (int kw = 0; kw < 3; ++kw) {
            y = fmaf(wt[ci * 9 + 0 * 3 + kw], r0[kw * 3 + ci], y);
            y = fmaf(wt[ci * 9 + 1 * 3 + kw], r1[kw * 3 + ci], y);
            y = fmaf(wt[ci * 9 + 2 * 3 + kw], r2[kw * 3 + ci], y);
        }
    }
    return y;
}

template <int MODE>
__global__ __launch_bounds__(256) void k_conv(const float* __restrict__ x,
                                              const float* __restrict__ cw,
                                              const float* __restrict__ cb,
                                              float* __restrict__ ws) {
    const int lane = threadIdx.x & 63;
    const int wv   = threadIdx.x >> 6;
    const int b    = blockIdx.y;
    const int col  = (blockIdx.x << 2) + wv;

    float wt[27];
#pragma unroll
    for (int k = 0; k < 27; ++k) wt[k] = cw[lane * 27 + k];
    const float bias = cb[lane];

    float A = 0.f, Bc = 0.f;
    if (MODE == 1) { A = ws[OFF_A + lane]; Bc = ws[OFF_B + lane]; }

    const float* xb = x + (size_t)b * (HH * WW * 3);

    float w0[9], w1[9], w2[9];
    loadrow(xb, -1, col, w0);
    loadrow(xb, 0, col, w1);
    loadrow(xb, 1, col, w2);

    float acc_s = 0.f, acc_q = 0.f;

#define DO_ONE(A0, A1, A2)                                   \
    {                                                        \
        float y = dorow(wt, bias, A0, A1, A2);               \
        if (MODE == 0) {                                     \
            acc_s += y;                                      \
            acc_q = fmaf(y, y, acc_q);                       \
        } else {                                             \
            float t = fmaf(y, A, Bc);                        \
            t = fmaxf(t, 0.f);                               \
            acc_s += t;                                      \
        }                                                    \
    }

    for (int r = 0; r < 255; r += 3) {
        DO_ONE(w0, w1, w2); loadrow(xb, r + 2, col, w0);
        DO_ONE(w1, w2, w0); loadrow(xb, r + 3, col, w1);
        DO_ONE(w2, w0, w1); loadrow(xb, r + 4, col, w2);
    }
    DO_ONE(w0, w1, w2);
#undef DO_ONE

    __shared__ float red[4][64][2];
    red[wv][lane][0] = acc_s;
    if (MODE == 0) red[wv][lane][1] = acc_q;
    __syncthreads();
    if (wv == 0) {
        float S = red[0][lane][0] + red[1][lane][0] + red[2][lane][0] + red[3][lane][0];
        if (MODE == 0) {
            float Q = red[0][lane][1] + red[1][lane][1] + red[2][lane][1] + red[3][lane][1];
            atomicAdd(&ws[OFF_CHSUM + lane], S);
            atomicAdd(&ws[OFF_CHSQ + lane], Q);
        } else {
            atomicAdd(&ws[OFF_FEAT + b * 64 + lane], S);
        }
    }
}

// ---------------- tail kernels ----------------

__global__ void k_stats(const float* __restrict__ bn_w, const float* __restrict__ bn_b,
                        float* __restrict__ ws) {
    int c = threadIdx.x;
    if (c < 64) {
        const float invN = 1.f / (float)(BB * HH * WW);
        float mu  = ws[OFF_CHSUM + c] * invN;
        float var = ws[OFF_CHSQ + c] * invN - mu * mu;
        float rs  = rsqrtf(var + 1e-5f);
        float A   = rs * bn_w[c];
        ws[OFF_A + c] = A;
        ws[OFF_B + c] = bn_b[c] - mu * A;
    }
}

__global__ void k_volt(const float* __restrict__ fcw, const float* __restrict__ fcb,
                       float* __restrict__ ws) {
    __shared__ float sv[16 * 3];
    int t = threadIdx.x;
    if (t < 16) {
        const float inv = 1.f / 65536.f;
        float raw[5];
#pragma unroll
        for (int j = 0; j < 5; ++j) {
            float a = fcb[j];
            for (int c2 = 0; c2 < 64; ++c2)
                a = fmaf(fcw[j * 64 + c2], ws[OFF_FEAT + t * 64 + c2] * inv, a);
            raw[j] = a;
        }
#define CS(i, j)                              \
        {                                     \
            float lo = fminf(raw[i], raw[j]); \
            float hi = fmaxf(raw[i], raw[j]); \
            raw[i] = lo;                      \
            raw[j] = hi;                      \
        }
        CS(0, 1) CS(3, 4) CS(2, 4) CS(2, 3) CS(0, 3) CS(0, 2) CS(1, 4) CS(1, 3) CS(1, 2)
#undef CS
        float mn = raw[0], mx = raw[4];
        float s = 10.f / (mx - mn + 1e-8f);
        sv[t * 3 + 0] = (raw[1] - mn) * s;
        sv[t * 3 + 1] = (raw[2] - mn) * s;
        sv[t * 3 + 2] = (raw[3] - mn) * s;
    }
    __syncthreads();
    for (int i = t; i < SRF_N; i += 256) {
        int b = i / 93, rr = i % 93, c2 = rr / 31, a = rr % 31;
        float band = 400.f + (300.f * (float)a) / 31.f;
        float v = sv[b * 3 + c2];
        float sh = sinf(0.031415926535897934f / v);
        ws[OFF_SRF + i] = (sh * sh) / (band * 1e-6f);
    }
}

__global__ __launch_bounds__(256) void k_apply(const float* __restrict__ xh,
                                               const float* __restrict__ ws,
                                               float* __restrict__ out) {
    __shared__ float4 s_srf[31];
    __shared__ float s_x[256 * 31];
    __shared__ float s_o[256 * 3];
    int t = threadIdx.x;
    int blk = blockIdx.x;
    int b = blk >> 8;
    size_t pix0 = (size_t)blk << 8;

    if (t < 124) {
        int a = t >> 2, c2 = t & 3;
        ((float*)s_srf)[t] = (c2 < 3) ? ws[OFF_SRF + b * 93 + c2 * 31 + a] : 0.f;
    }
    const float4* xg = (const float4*)(xh + pix0 * 31);
    float4* sx4 = (float4*)s_x;
#pragma unroll
    for (int i = 0; i < 8; ++i) {
        int idx = t + (i << 8);
        if (idx < 1984) sx4[idx] = xg[idx];
    }
    __syncthreads();

    float a0 = 0.f, a1 = 0.f, a2 = 0.f;
    const float* px = s_x + t * 31;
#pragma unroll
    for (int a = 0; a < 31; ++a) {
        float v = px[a];
        float4 s = s_srf[a];
        a0 = fmaf(v, s.x, a0);
        a1 = fmaf(v, s.y, a1);
        a2 = fmaf(v, s.z, a2);
    }
    s_o[t * 3 + 0] = a0;
    s_o[t * 3 + 1] = a1;
    s_o[t * 3 + 2] = a2;
    __syncthreads();
    float* ob = out + pix0 * 3;
#pragma unroll
    for (int i = 0; i < 3; ++i) ob[t + (i << 8)] = s_o[t + (i << 8)];
}

extern "C" void kernel_launch(void* const* d_in, const int* in_sizes, int n_in,
                              void* d_out, int out_size, void* d_ws, size_t ws_size,
                              hipStream_t stream) {
    const float* x    = (const float*)d_in[0];
    const float* xhsi = (const float*)d_in[1];
    const float* cw   = (const float*)d_in[2];
    const float* cb   = (const float*)d_in[3];
    const float* bnw  = (const float*)d_in[4];
    const float* bnb  = (const float*)d_in[5];
    const float* fcw  = (const float*)d_in[6];
    const float* fcb  = (const float*)d_in[7];
    float* out = (float*)d_out;
    float* ws  = (float*)d_ws;

    hipLaunchKernelGGL(k_init, dim3(5), dim3(256), 0, stream, ws);
    if (ws_size >= WS_NEED_BYTES) {
        hipLaunchKernelGGL(k_pad, dim3((PW * PW + 255) / 256, 16), dim3(256), 0, stream,
                           x, ws);
        hipLaunchKernelGGL((k_convp<0>), dim3(64, 16, 2), dim3(256), 0, stream, cw, cb, ws);
        hipLaunchKernelGGL(k_stats, dim3(1), dim3(64), 0, stream, bnw, bnb, ws);
        hipLaunchKernelGGL((k_convp<1>), dim3(64, 16, 2), dim3(256), 0, stream, cw, cb, ws);
    } else {
        hipLaunchKernelGGL((k_conv<0>), dim3(64, 16), dim3(256), 0, stream, x, cw, cb, ws);
        hipLaunchKernelGGL(k_stats, dim3(1), dim3(64), 0, stream, bnw, bnb, ws);
        hipLaunchKernelGGL((k_conv<1>), dim3(64, 16), dim3(256), 0, stream, x, cw, cb, ws);
    }
    hipLaunchKernelGGL(k_volt, dim3(1), dim3(256), 0, stream, fcw, fcb, ws);
    hipLaunchKernelGGL(k_apply, dim3(4096), dim3(256), 0, stream, xhsi, ws, out);
}

// Round 4
// 173.954 us; speedup vs baseline: 1.4802x; 1.4802x over previous
//
#include <hip/hip_runtime.h>
#include <math.h>

#define BB 16
#define HH 256
#define WW 256
#define PW 258

// ws layout in floats
#define OFF_CHSUM 0      // [64]
#define OFF_CHSQ  64     // [64]
#define OFF_A     128    // [64]  rsig * bn_w
#define OFF_B     192    // [64]  bn_b - mu * A
#define OFF_FEAT  256    // [16*64] pooled relu sums (pre-division)
#define OFF_SRF   1280   // [16*3*31]
#define SRF_N     (16 * 93)
#define OFF_X4    4096   // padded input: 16 x 258 x 258 x float4
#define X4_FLOATS (16 * PW * PW * 4)
#define WS_NEED_BYTES ((size_t)(OFF_X4 + X4_FLOATS) * 4)

__global__ void k_init(float* __restrict__ ws) {
    int i = blockIdx.x * 256 + threadIdx.x;
    if (i < 1280) ws[i] = 0.f;
}

// ---------------- padded-layout fast path ----------------

__global__ __launch_bounds__(256) void k_pad(const float* __restrict__ x,
                                             float* __restrict__ ws) {
    int b = blockIdx.y;
    int i = blockIdx.x * 256 + threadIdx.x;
    if (i >= PW * PW) return;
    int pr = i / PW, pc = i % PW;
    float4 v = make_float4(0.f, 0.f, 0.f, 0.f);
    if (pr >= 1 && pr <= HH && pc >= 1 && pc <= WW) {
        const float* p = x + (((size_t)b * HH + (pr - 1)) * WW + (pc - 1)) * 3;
        v.x = p[0]; v.y = p[1]; v.z = p[2];
    }
    ((float4*)(ws + OFF_X4))[((size_t)b * PW + pr) * PW + pc] = v;
}

// LDS-staged conv. Block = 4 waves; wave wv -> output col c0+wv; 128 rows/block.
// Panel (130 rows x 6 float4 = 12.5 KB) staged once; compute reads broadcast LDS.
// MODE 0: per-channel sum/sumsq.  MODE 1: BN+ReLU, per-(b,c) pool sum.
template <int MODE>
__global__ __launch_bounds__(256) void k_convl(const float* __restrict__ cw,
                                               const float* __restrict__ cb,
                                               float* __restrict__ ws) {
    __shared__ float4 pan[130 * 6];
    __shared__ float red[4][64][2];
    const int t    = threadIdx.x;
    const int lane = t & 63;             // output channel
    const int wv   = t >> 6;             // wave id 0..3
    const int b    = blockIdx.y;
    const int c0   = blockIdx.x * 4;     // padded col base (== output col base)
    const int r0   = blockIdx.z * 128;   // padded row base (== output row base)

    // cooperative stage: 780 float4, coalesced-ish (96B runs)
    {
        const float4* src = (const float4*)(ws + OFF_X4) + ((size_t)(b * PW + r0)) * PW + c0;
        for (int e = t; e < 780; e += 256) {
            int row = e / 6, c = e - row * 6;
            pan[e] = src[(size_t)row * PW + c];
        }
    }

    float wt[27];
#pragma unroll
    for (int k = 0; k < 27; ++k) wt[k] = cw[lane * 27 + k];
    const float bias = cb[lane];
    float A = 0.f, Bc = 0.f;
    if (MODE == 1) { A = ws[OFF_A + lane]; Bc = ws[OFF_B + lane]; }

    __syncthreads();

    const float4* pw = pan + wv;   // row r, col j -> pw[r*6 + j]
    float4 Q0[3], Q1[3], Q2[3];
#define LDR(R, r) { R[0] = pw[(r) * 6]; R[1] = pw[(r) * 6 + 1]; R[2] = pw[(r) * 6 + 2]; }
    LDR(Q0, 0) LDR(Q1, 1)

    float acc_s = 0.f, acc_q = 0.f;

#define PX(RA, RB, RC)                                                        \
    {                                                                         \
        float y0 = bias, y1 = 0.f, y2 = 0.f;                                  \
        y0 = fmaf(wt[0], RA[0].x, y0); y0 = fmaf(wt[1], RA[1].x, y0);         \
        y0 = fmaf(wt[2], RA[2].x, y0); y0 = fmaf(wt[3], RB[0].x, y0);         \
        y0 = fmaf(wt[4], RB[1].x, y0); y0 = fmaf(wt[5], RB[2].x, y0);         \
        y0 = fmaf(wt[6], RC[0].x, y0); y0 = fmaf(wt[7], RC[1].x, y0);         \
        y0 = fmaf(wt[8], RC[2].x, y0);                                        \
        y1 = fmaf(wt[9], RA[0].y, y1); y1 = fmaf(wt[10], RA[1].y, y1);        \
        y1 = fmaf(wt[11], RA[2].y, y1); y1 = fmaf(wt[12], RB[0].y, y1);       \
        y1 = fmaf(wt[13], RB[1].y, y1); y1 = fmaf(wt[14], RB[2].y, y1);       \
        y1 = fmaf(wt[15], RC[0].y, y1); y1 = fmaf(wt[16], RC[1].y, y1);       \
        y1 = fmaf(wt[17], RC[2].y, y1);                                       \
        y2 = fmaf(wt[18], RA[0].z, y2); y2 = fmaf(wt[19], RA[1].z, y2);       \
        y2 = fmaf(wt[20], RA[2].z, y2); y2 = fmaf(wt[21], RB[0].z, y2);       \
        y2 = fmaf(wt[22], RB[1].z, y2); y2 = fmaf(wt[23], RB[2].z, y2);       \
        y2 = fmaf(wt[24], RC[0].z, y2); y2 = fmaf(wt[25], RC[1].z, y2);       \
        y2 = fmaf(wt[26], RC[2].z, y2);                                       \
        float y = (y0 + y1) + y2;                                             \
        if (MODE == 0) {                                                      \
            acc_s += y;                                                       \
            acc_q = fmaf(y, y, acc_q);                                        \
        } else {                                                              \
            float tv = fmaxf(fmaf(y, A, Bc), 0.f);                            \
            acc_s += tv;                                                      \
        }                                                                     \
    }

    // pixels 0..125 (rows read up to 128)
#pragma unroll 1
    for (int i = 0; i < 42; ++i) {
        int r = 3 * i;
        LDR(Q2, r + 2) PX(Q0, Q1, Q2)
        LDR(Q0, r + 3) PX(Q1, Q2, Q0)
        LDR(Q1, r + 4) PX(Q2, Q0, Q1)
    }
    // pixels 126,127 (rows 126..129)
    LDR(Q2, 128) PX(Q0, Q1, Q2)
    LDR(Q0, 129) PX(Q1, Q2, Q0)
#undef PX
#undef LDR

    red[wv][lane][0] = acc_s;
    if (MODE == 0) red[wv][lane][1] = acc_q;
    __syncthreads();
    if (wv == 0) {
        float S = red[0][lane][0] + red[1][lane][0] + red[2][lane][0] + red[3][lane][0];
        if (MODE == 0) {
            float Q = red[0][lane][1] + red[1][lane][1] + red[2][lane][1] + red[3][lane][1];
            atomicAdd(&ws[OFF_CHSUM + lane], S);
            atomicAdd(&ws[OFF_CHSQ + lane], Q);
        } else {
            atomicAdd(&ws[OFF_FEAT + b * 64 + lane], S);
        }
    }
}

// ---------------- fallback (round-1) conv, used only if ws too small ----------------

__device__ __forceinline__ void loadrow(const float* __restrict__ xb, int rr, int col,
                                        float* dst) {
    if (rr < 0 || rr >= HH) {
#pragma unroll
        for (int k = 0; k < 9; ++k) dst[k] = 0.f;
        return;
    }
    const float* p = xb + rr * (WW * 3);
#pragma unroll
    for (int kw = 0; kw < 3; ++kw) {
        int cc = col - 1 + kw;
        if (cc >= 0 && cc < WW) {
            dst[kw * 3 + 0] = p[cc * 3 + 0];
            dst[kw * 3 + 1] = p[cc * 3 + 1];
            dst[kw * 3 + 2] = p[cc * 3 + 2];
        } else {
            dst[kw * 3 + 0] = 0.f; dst[kw * 3 + 1] = 0.f; dst[kw * 3 + 2] = 0.f;
        }
    }
}

__device__ __forceinline__ float dorow(const float* wt, float bias,
                                       const float* r0, const float* r1, const float* r2) {
    float y = bias;
#pragma unroll
    for (int ci = 0; ci < 3; ++ci) {
#pragma unroll
        for (int kw = 0; kw < 3; ++kw) {
            y = fmaf(wt[ci * 9 + 0 * 3 + kw], r0[kw * 3 + ci], y);
            y = fmaf(wt[ci * 9 + 1 * 3 + kw], r1[kw * 3 + ci], y);
            y = fmaf(wt[ci * 9 + 2 * 3 + kw], r2[kw * 3 + ci], y);
        }
    }
    return y;
}

template <int MODE>
__global__ __launch_bounds__(256) void k_conv(const float* __restrict__ x,
                                              const float* __restrict__ cw,
                                              const float* __restrict__ cb,
                                              float* __restrict__ ws) {
    const int lane = threadIdx.x & 63;
    const int wv   = threadIdx.x >> 6;
    const int b    = blockIdx.y;
    const int col  = (blockIdx.x << 2) + wv;

    float wt[27];
#pragma unroll
    for (int k = 0; k < 27; ++k) wt[k] = cw[lane * 27 + k];
    const float bias = cb[lane];

    float A = 0.f, Bc = 0.f;
    if (MODE == 1) { A = ws[OFF_A + lane]; Bc = ws[OFF_B + lane]; }

    const float* xb = x + (size_t)b * (HH * WW * 3);

    float w0[9], w1[9], w2[9];
    loadrow(xb, -1, col, w0);
    loadrow(xb, 0, col, w1);
    loadrow(xb, 1, col, w2);

    float acc_s = 0.f, acc_q = 0.f;

#define DO_ONE(A0, A1, A2)                                   \
    {                                                        \
        float y = dorow(wt, bias, A0, A1, A2);               \
        if (MODE == 0) {                                     \
            acc_s += y;                                      \
            acc_q = fmaf(y, y, acc_q);                       \
        } else {                                             \
            float t2 = fmaf(y, A, Bc);                       \
            t2 = fmaxf(t2, 0.f);                             \
            acc_s += t2;                                     \
        }                                                    \
    }

    for (int r = 0; r < 255; r += 3) {
        DO_ONE(w0, w1, w2); loadrow(xb, r + 2, col, w0);
        DO_ONE(w1, w2, w0); loadrow(xb, r + 3, col, w1);
        DO_ONE(w2, w0, w1); loadrow(xb, r + 4, col, w2);
    }
    DO_ONE(w0, w1, w2);
#undef DO_ONE

    __shared__ float red[4][64][2];
    red[wv][lane][0] = acc_s;
    if (MODE == 0) red[wv][lane][1] = acc_q;
    __syncthreads();
    if (wv == 0) {
        float S = red[0][lane][0] + red[1][lane][0] + red[2][lane][0] + red[3][lane][0];
        if (MODE == 0) {
            float Q = red[0][lane][1] + red[1][lane][1] + red[2][lane][1] + red[3][lane][1];
            atomicAdd(&ws[OFF_CHSUM + lane], S);
            atomicAdd(&ws[OFF_CHSQ + lane], Q);
        } else {
            atomicAdd(&ws[OFF_FEAT + b * 64 + lane], S);
        }
    }
}

// ---------------- tail kernels ----------------

__global__ void k_stats(const float* __restrict__ bn_w, const float* __restrict__ bn_b,
                        float* __restrict__ ws) {
    int c = threadIdx.x;
    if (c < 64) {
        const float invN = 1.f / (float)(BB * HH * WW);
        float mu  = ws[OFF_CHSUM + c] * invN;
        float var = ws[OFF_CHSQ + c] * invN - mu * mu;
        float rs  = rsqrtf(var + 1e-5f);
        float A   = rs * bn_w[c];
        ws[OFF_A + c] = A;
        ws[OFF_B + c] = bn_b[c] - mu * A;
    }
}

__global__ void k_volt(const float* __restrict__ fcw, const float* __restrict__ fcb,
                       float* __restrict__ ws) {
    __shared__ float sv[16 * 3];
    int t = threadIdx.x;
    if (t < 16) {
        const float inv = 1.f / 65536.f;
        float raw[5];
#pragma unroll
        for (int j = 0; j < 5; ++j) {
            float a = fcb[j];
            for (int c2 = 0; c2 < 64; ++c2)
                a = fmaf(fcw[j * 64 + c2], ws[OFF_FEAT + t * 64 + c2] * inv, a);
            raw[j] = a;
        }
#define CS(i, j)                              \
        {                                     \
            float lo = fminf(raw[i], raw[j]); \
            float hi = fmaxf(raw[i], raw[j]); \
            raw[i] = lo;                      \
            raw[j] = hi;                      \
        }
        CS(0, 1) CS(3, 4) CS(2, 4) CS(2, 3) CS(0, 3) CS(0, 2) CS(1, 4) CS(1, 3) CS(1, 2)
#undef CS
        float mn = raw[0], mx = raw[4];
        float s = 10.f / (mx - mn + 1e-8f);
        sv[t * 3 + 0] = (raw[1] - mn) * s;
        sv[t * 3 + 1] = (raw[2] - mn) * s;
        sv[t * 3 + 2] = (raw[3] - mn) * s;
    }
    __syncthreads();
    for (int i = t; i < SRF_N; i += 256) {
        int b = i / 93, rr = i % 93, c2 = rr / 31, a = rr % 31;
        float band = 400.f + (300.f * (float)a) / 31.f;
        float v = sv[b * 3 + c2];
        float sh = sinf(0.031415926535897934f / v);
        ws[OFF_SRF + i] = (sh * sh) / (band * 1e-6f);
    }
}

__global__ __launch_bounds__(256) void k_apply(const float* __restrict__ xh,
                                               const float* __restrict__ ws,
                                               float* __restrict__ out) {
    __shared__ float4 s_srf[31];
    __shared__ float s_x[256 * 31];
    __shared__ float s_o[256 * 3];
    int t = threadIdx.x;
    int blk = blockIdx.x;
    int b = blk >> 8;
    size_t pix0 = (size_t)blk << 8;

    if (t < 124) {
        int a = t >> 2, c2 = t & 3;
        ((float*)s_srf)[t] = (c2 < 3) ? ws[OFF_SRF + b * 93 + c2 * 31 + a] : 0.f;
    }
    const float4* xg = (const float4*)(xh + pix0 * 31);
    float4* sx4 = (float4*)s_x;
#pragma unroll
    for (int i = 0; i < 8; ++i) {
        int idx = t + (i << 8);
        if (idx < 1984) sx4[idx] = xg[idx];
    }
    __syncthreads();

    float a0 = 0.f, a1 = 0.f, a2 = 0.f;
    const float* px = s_x + t * 31;
#pragma unroll
    for (int a = 0; a < 31; ++a) {
        float v = px[a];
        float4 s = s_srf[a];
        a0 = fmaf(v, s.x, a0);
        a1 = fmaf(v, s.y, a1);
        a2 = fmaf(v, s.z, a2);
    }
    s_o[t * 3 + 0] = a0;
    s_o[t * 3 + 1] = a1;
    s_o[t * 3 + 2] = a2;
    __syncthreads();
    float* ob = out + pix0 * 3;
#pragma unroll
    for (int i = 0; i < 3; ++i) ob[t + (i << 8)] = s_o[t + (i << 8)];
}

extern "C" void kernel_launch(void* const* d_in, const int* in_sizes, int n_in,
                              void* d_out, int out_size, void* d_ws, size_t ws_size,
                              hipStream_t stream) {
    const float* x    = (const float*)d_in[0];
    const float* xhsi = (const float*)d_in[1];
    const float* cw   = (const float*)d_in[2];
    const float* cb   = (const float*)d_in[3];
    const float* bnw  = (const float*)d_in[4];
    const float* bnb  = (const float*)d_in[5];
    const float* fcw  = (const float*)d_in[6];
    const float* fcb  = (const float*)d_in[7];
    float* out = (float*)d_out;
    float* ws  = (float*)d_ws;

    hipLaunchKernelGGL(k_init, dim3(5), dim3(256), 0, stream, ws);
    if (ws_size >= WS_NEED_BYTES) {
        hipLaunchKernelGGL(k_pad, dim3((PW * PW + 255) / 256, 16), dim3(256), 0, stream,
                           x, ws);
        hipLaunchKernelGGL((k_convl<0>), dim3(64, 16, 2), dim3(256), 0, stream, cw, cb, ws);
        hipLaunchKernelGGL(k_stats, dim3(1), dim3(64), 0, stream, bnw, bnb, ws);
        hipLaunchKernelGGL((k_convl<1>), dim3(64, 16, 2), dim3(256), 0, stream, cw, cb, ws);
    } else {
        hipLaunchKernelGGL((k_conv<0>), dim3(64, 16), dim3(256), 0, stream, x, cw, cb, ws);
        hipLaunchKernelGGL(k_stats, dim3(1), dim3(64), 0, stream, bnw, bnb, ws);
        hipLaunchKernelGGL((k_conv<1>), dim3(64, 16), dim3(256), 0, stream, x, cw, cb, ws);
    }
    hipLaunchKernelGGL(k_volt, dim3(1), dim3(256), 0, stream, fcw, fcb, ws);
    hipLaunchKernelGGL(k_apply, dim3(4096), dim3(256), 0, stream, xhsi, ws, out);
}

// Round 5
// 152.907 us; speedup vs baseline: 1.6840x; 1.1376x over previous
//
#include <hip/hip_runtime.h>
#include <math.h>

#define BB 16
#define HH 256
#define WW 256

// ws layout in floats
#define OFF_CHSUM 0      // [64]
#define OFF_CHSQ  64     // [64]
#define OFF_A     128    // [64]  rsig * bn_w
#define OFF_B     192    // [64]  bn_b - mu * A
#define OFF_FEAT  256    // [16*64] pooled relu sums (pre-division)
#define OFF_SRF   1280   // [16*3*31]
#define SRF_N     (16 * 93)

typedef __attribute__((ext_vector_type(4))) float v4;
typedef __attribute__((ext_vector_type(2))) float v2;

struct RowW { v4 q[4]; v2 e; };   // 18 floats: window for 4 output cols

__global__ void k_init(float* __restrict__ ws) {
    int i = blockIdx.x * 256 + threadIdx.x;
    if (i < 1280) ws[i] = 0.f;
}

// Strip conv: block covers 16 out-cols x 64 out-rows of one image.
// 4 waves; wave wv handles out-cols c0+4wv .. c0+4wv+3. lane = out-channel.
// LDS pan[66][56]: row l <-> global row r0-1+l; float j <-> (col c0-1+j/3, ch j%3).
// All compute-phase LDS reads are wave-uniform (broadcast, conflict-free).
// MODE 0: per-channel sum/sumsq.  MODE 1: BN+ReLU, per-(b,c) pool sum.
template <int MODE>
__global__ __launch_bounds__(256) void k_convs(const float* __restrict__ x,
                                               const float* __restrict__ cw,
                                               const float* __restrict__ cb,
                                               float* __restrict__ ws) {
    __shared__ float pan[66 * 56];
    __shared__ float red[4][64][2];
    const int t    = threadIdx.x;
    const int lane = t & 63;
    const int wv   = t >> 6;
    const int b    = blockIdx.y;
    const int c0   = blockIdx.x * 16;
    const int r0   = blockIdx.z * 64;

    // ---- stage: 66 rows x 54 contiguous floats from x (NHWC), border-predicated
    {
        const float* xb = x + (size_t)b * (HH * WW * 3);
        const int gc0 = (c0 - 1) * 3;
        for (int e = t; e < 66 * 54; e += 256) {
            int l = e / 54;
            int j = e - l * 54;
            int gr = r0 - 1 + l;
            int gcf = gc0 + j;
            bool ok = ((unsigned)gr < 256u) && ((unsigned)gcf < 768u);
            float v = 0.f;
            if (ok) v = xb[(size_t)gr * 768 + gcf];
            pan[l * 56 + j] = v;
        }
    }

    float wt[27];
#pragma unroll
    for (int k = 0; k < 27; ++k) wt[k] = cw[lane * 27 + k];
    const float bias = cb[lane];
    float A = 0.f, Bc = 0.f;
    if (MODE == 1) { A = ws[OFF_A + lane]; Bc = ws[OFF_B + lane]; }

    __syncthreads();

    const float* base = pan + wv * 12;   // wave window start: 48B-aligned

#define LDR(R, l)                                                   \
    {                                                               \
        const float* p = base + (l) * 56;                           \
        R.q[0] = *(const v4*)(p);                                   \
        R.q[1] = *(const v4*)(p + 4);                               \
        R.q[2] = *(const v4*)(p + 8);                               \
        R.q[3] = *(const v4*)(p + 12);                              \
        R.e    = *(const v2*)(p + 16);                              \
    }
#define U(R, n) ((n) < 16 ? (R).q[(n) >> 2][(n) & 3] : (R).e[(n) - 16])
#define T1(R, kh, j, kw, ci, y) \
    y = fmaf(wt[(ci) * 9 + (kh) * 3 + (kw)], U(R, 3 * ((j) + (kw)) + (ci)), y);
#define ROW9(R, kh, j, y)                                           \
    T1(R, kh, j, 0, 0, y) T1(R, kh, j, 0, 1, y) T1(R, kh, j, 0, 2, y) \
    T1(R, kh, j, 1, 0, y) T1(R, kh, j, 1, 1, y) T1(R, kh, j, 1, 2, y) \
    T1(R, kh, j, 2, 0, y) T1(R, kh, j, 2, 1, y) T1(R, kh, j, 2, 2, y)
#define PX1(j, RA, RB, RC, accs, accq)                              \
    {                                                               \
        float y = bias;                                             \
        ROW9(RA, 0, j, y) ROW9(RB, 1, j, y) ROW9(RC, 2, j, y)       \
        if (MODE == 0) { accs += y; accq = fmaf(y, y, accq); }      \
        else { float tv = fmaxf(fmaf(y, A, Bc), 0.f); accs += tv; } \
    }
#define PX4(RA, RB, RC)                                             \
    PX1(0, RA, RB, RC, as0, aq0) PX1(1, RA, RB, RC, as1, aq1)       \
    PX1(2, RA, RB, RC, as0, aq0) PX1(3, RA, RB, RC, as1, aq1)

    RowW R0, R1, R2, R3;
    LDR(R0, 0) LDR(R1, 1) LDR(R2, 2) LDR(R3, 3)
    float as0 = 0.f, aq0 = 0.f, as1 = 0.f, aq1 = 0.f;

#pragma unroll 1
    for (int i = 0; i < 15; ++i) {
        const int l = 4 * i;
        PX4(R0, R1, R2) LDR(R0, l + 4)
        PX4(R1, R2, R3) LDR(R1, l + 5)
        PX4(R2, R3, R0) LDR(R2, l + 6)
        PX4(R3, R0, R1) LDR(R3, l + 7)
    }
    // out rows 60..63 (local window rows 60..65)
    PX4(R0, R1, R2) LDR(R0, 64)
    PX4(R1, R2, R3) LDR(R1, 65)
    PX4(R2, R3, R0)
    PX4(R3, R0, R1)

#undef PX4
#undef PX1
#undef ROW9
#undef T1
#undef U
#undef LDR

    float acc_s = as0 + as1;
    float acc_q = aq0 + aq1;

    red[wv][lane][0] = acc_s;
    if (MODE == 0) red[wv][lane][1] = acc_q;
    __syncthreads();
    if (wv == 0) {
        float S = red[0][lane][0] + red[1][lane][0] + red[2][lane][0] + red[3][lane][0];
        if (MODE == 0) {
            float Q = red[0][lane][1] + red[1][lane][1] + red[2][lane][1] + red[3][lane][1];
            atomicAdd(&ws[OFF_CHSUM + lane], S);
            atomicAdd(&ws[OFF_CHSQ + lane], Q);
        } else {
            atomicAdd(&ws[OFF_FEAT + b * 64 + lane], S);
        }
    }
}

// ---------------- tail kernels ----------------

__global__ void k_stats(const float* __restrict__ bn_w, const float* __restrict__ bn_b,
                        float* __restrict__ ws) {
    int c = threadIdx.x;
    if (c < 64) {
        const float invN = 1.f / (float)(BB * HH * WW);
        float mu  = ws[OFF_CHSUM + c] * invN;
        float var = ws[OFF_CHSQ + c] * invN - mu * mu;
        float rs  = rsqrtf(var + 1e-5f);
        float A   = rs * bn_w[c];
        ws[OFF_A + c] = A;
        ws[OFF_B + c] = bn_b[c] - mu * A;
    }
}

__global__ void k_volt(const float* __restrict__ fcw, const float* __restrict__ fcb,
                       float* __restrict__ ws) {
    __shared__ float sv[16 * 3];
    int t = threadIdx.x;
    if (t < 16) {
        const float inv = 1.f / 65536.f;
        float raw[5];
#pragma unroll
        for (int j = 0; j < 5; ++j) {
            float a = fcb[j];
            for (int c2 = 0; c2 < 64; ++c2)
                a = fmaf(fcw[j * 64 + c2], ws[OFF_FEAT + t * 64 + c2] * inv, a);
            raw[j] = a;
        }
#define CS(i, j)                              \
        {                                     \
            float lo = fminf(raw[i], raw[j]); \
            float hi = fmaxf(raw[i], raw[j]); \
            raw[i] = lo;                      \
            raw[j] = hi;                      \
        }
        CS(0, 1) CS(3, 4) CS(2, 4) CS(2, 3) CS(0, 3) CS(0, 2) CS(1, 4) CS(1, 3) CS(1, 2)
#undef CS
        float mn = raw[0], mx = raw[4];
        float s = 10.f / (mx - mn + 1e-8f);
        sv[t * 3 + 0] = (raw[1] - mn) * s;
        sv[t * 3 + 1] = (raw[2] - mn) * s;
        sv[t * 3 + 2] = (raw[3] - mn) * s;
    }
    __syncthreads();
    for (int i = t; i < SRF_N; i += 256) {
        int b = i / 93, rr = i % 93, c2 = rr / 31, a = rr % 31;
        float band = 400.f + (300.f * (float)a) / 31.f;
        float v = sv[b * 3 + c2];
        float sh = sinf(0.031415926535897934f / v);
        ws[OFF_SRF + i] = (sh * sh) / (band * 1e-6f);
    }
}

__global__ __launch_bounds__(256) void k_apply(const float* __restrict__ xh,
                                               const float* __restrict__ ws,
                                               float* __restrict__ out) {
    __shared__ float4 s_srf[31];
    __shared__ float s_x[256 * 31];
    __shared__ float s_o[256 * 3];
    int t = threadIdx.x;
    int blk = blockIdx.x;
    int b = blk >> 8;
    size_t pix0 = (size_t)blk << 8;

    if (t < 124) {
        int a = t >> 2, c2 = t & 3;
        ((float*)s_srf)[t] = (c2 < 3) ? ws[OFF_SRF + b * 93 + c2 * 31 + a] : 0.f;
    }
    const float4* xg = (const float4*)(xh + pix0 * 31);
    float4* sx4 = (float4*)s_x;
#pragma unroll
    for (int i = 0; i < 8; ++i) {
        int idx = t + (i << 8);
        if (idx < 1984) sx4[idx] = xg[idx];
    }
    __syncthreads();

    float a0 = 0.f, a1 = 0.f, a2 = 0.f;
    const float* px = s_x + t * 31;
#pragma unroll
    for (int a = 0; a < 31; ++a) {
        float v = px[a];
        float4 s = s_srf[a];
        a0 = fmaf(v, s.x, a0);
        a1 = fmaf(v, s.y, a1);
        a2 = fmaf(v, s.z, a2);
    }
    s_o[t * 3 + 0] = a0;
    s_o[t * 3 + 1] = a1;
    s_o[t * 3 + 2] = a2;
    __syncthreads();
    float* ob = out + pix0 * 3;
#pragma unroll
    for (int i = 0; i < 3; ++i) ob[t + (i << 8)] = s_o[t + (i << 8)];
}

extern "C" void kernel_launch(void* const* d_in, const int* in_sizes, int n_in,
                              void* d_out, int out_size, void* d_ws, size_t ws_size,
                              hipStream_t stream) {
    const float* x    = (const float*)d_in[0];
    const float* xhsi = (const float*)d_in[1];
    const float* cw   = (const float*)d_in[2];
    const float* cb   = (const float*)d_in[3];
    const float* bnw  = (const float*)d_in[4];
    const float* bnb  = (const float*)d_in[5];
    const float* fcw  = (const float*)d_in[6];
    const float* fcb  = (const float*)d_in[7];
    float* out = (float*)d_out;
    float* ws  = (float*)d_ws;

    hipLaunchKernelGGL(k_init, dim3(5), dim3(256), 0, stream, ws);
    hipLaunchKernelGGL((k_convs<0>), dim3(16, 16, 4), dim3(256), 0, stream, x, cw, cb, ws);
    hipLaunchKernelGGL(k_stats, dim3(1), dim3(64), 0, stream, bnw, bnb, ws);
    hipLaunchKernelGGL((k_convs<1>), dim3(16, 16, 4), dim3(256), 0, stream, x, cw, cb, ws);
    hipLaunchKernelGGL(k_volt, dim3(1), dim3(256), 0, stream, fcw, fcb, ws);
    hipLaunchKernelGGL(k_apply, dim3(4096), dim3(256), 0, stream, xhsi, ws, out);
}

// Round 6
// 140.384 us; speedup vs baseline: 1.8342x; 1.0892x over previous
//
#include <hip/hip_runtime.h>
#include <hip/hip_bf16.h>
#include <math.h>

#define BB 16
#define HH 256
#define WW 256

// ws layout in floats
#define OFF_CHSUM 0      // [64]
#define OFF_CHSQ  64     // [64]
#define OFF_A     128    // [64]  rsig * bn_w
#define OFF_B     192    // [64]  bn_b - mu * A
#define OFF_FEAT  256    // [16*64] pooled relu sums (pre-division)
#define OFF_SRF   1280   // [16*3*31]
#define SRF_N     (16 * 93)

typedef __attribute__((ext_vector_type(8))) short bf16x8;
typedef __attribute__((ext_vector_type(4))) float f32x4;

union BFu { __hip_bfloat16 h; short s; };

__device__ __forceinline__ short bf_hi(float v, float& resid) {
    BFu u; u.h = __float2bfloat16(v);
    resid = v - __bfloat162float(u.h);
    return u.s;
}
__device__ __forceinline__ short bf_of(float v) {
    BFu u; u.h = __float2bfloat16(v);
    return u.s;
}

__global__ void k_init(float* __restrict__ ws) {
    int i = blockIdx.x * 256 + threadIdx.x;
    if (i < 1280) ws[i] = 0.f;
}

// Implicit-GEMM conv via split-bf16 MFMA.
// Block = 4 waves; wave wv owns cols [64wv, 64wv+64) of 4 image rows (blockIdx.x*4+rr).
// Per 16-px m-tile: lane l supplies A[px = m0+(l&15)][k = (l>>4)*8 + e],
// k = kh*9 + kw*3 + ci  <->  9 consecutive NHWC floats per kernel row.
// y = (Ah+Al)(Bh+Bl) ~= Ah*Bh + Ah*Bl + Al*Bh  (3 MFMAs, ~1.5e-5 rel err).
// MODE 0: per-channel sum/sumsq.  MODE 1: BN+ReLU, per-(b,c) pooled sum.
template <int MODE>
__global__ __launch_bounds__(256) void k_convm(const float* __restrict__ x,
                                               const float* __restrict__ cw,
                                               const float* __restrict__ cb,
                                               float* __restrict__ ws) {
    const int t    = threadIdx.x;
    const int lane = t & 63;
    const int wv   = t >> 6;
    const int b    = blockIdx.y;
    const int r0   = blockIdx.x * 4;
    const int s    = lane >> 4;      // k-slice 0..3
    const int mrow = lane & 15;      // px-in-mtile (A) / ch-in-ntile (B,C)
    const float* __restrict__ xb = x + (size_t)b * (HH * WW * 3);

    // ---- B fragments (once per wave): lane holds W[ch][k-slice] in im2col k-order
    bf16x8 bh[4], bl[4];
    float cbv[4], av[4], bvv[4];
#pragma unroll
    for (int n = 0; n < 4; ++n) {
        const int ch = n * 16 + mrow;
        cbv[n] = cb[ch];
        if (MODE == 1) { av[n] = ws[OFF_A + ch]; bvv[n] = ws[OFF_B + ch]; }
        else { av[n] = 0.f; bvv[n] = 0.f; }
#pragma unroll
        for (int e = 0; e < 8; ++e) {
            const int k = s * 8 + e;
            float w = 0.f;
            if (k < 27) {
                const int kh = (k >= 18) ? 2 : (k >= 9 ? 1 : 0);
                const int j  = k - kh * 9;
                const int kw2 = j / 3, ci = j - kw2 * 3;
                w = cw[ch * 27 + ci * 9 + kh * 3 + kw2];
            }
            float rs;
            bh[n][e] = bf_hi(w, rs);
            bl[n][e] = bf_of(rs);
        }
    }

    // ---- per-e window mapping constants
    int jm3[8];   // j - 3, or huge sentinel for k>=27 (forces col-check fail)
    int khof[8];  // kernel-row offset 0..2
#pragma unroll
    for (int e = 0; e < 8; ++e) {
        const int k = s * 8 + e;
        const int kh = (k >= 18) ? 2 : (k >= 9 ? 1 : 0);
        khof[e] = kh;
        jm3[e] = (k < 27) ? (k - kh * 9 - 3) : (1 << 20);
    }

    float a0[4] = {0.f, 0.f, 0.f, 0.f};   // MODE0: sum   MODE1: pooled relu sum
    float a1[4] = {0.f, 0.f, 0.f, 0.f};   // MODE0: sumsq

#pragma unroll 1
    for (int rr = 0; rr < 4; ++rr) {
        const int r = r0 + rr;
        int roff[8], rok[8];
#pragma unroll
        for (int e = 0; e < 8; ++e) {
            const int rowi = r - 1 + khof[e];
            rok[e]  = ((unsigned)rowi < 256u) ? 1 : 0;
            roff[e] = rowi * 768;
        }
#pragma unroll
        for (int cs = 0; cs < 4; ++cs) {
            const int c  = wv * 64 + cs * 16 + mrow;   // px col
            const int c3 = c * 3;
            float win[8];
#pragma unroll
            for (int e = 0; e < 8; ++e) {
                const int cf = c3 + jm3[e];
                const bool ok = ((unsigned)cf < 768u) && rok[e];
                int off = roff[e] + cf;
                off = ok ? off : 0;
                const float v = xb[off];
                win[e] = ok ? v : 0.f;
            }
            bf16x8 ah, al;
#pragma unroll
            for (int e = 0; e < 8; ++e) {
                float rs;
                ah[e] = bf_hi(win[e], rs);
                al[e] = bf_of(rs);
            }
#pragma unroll
            for (int n = 0; n < 4; ++n) {
                f32x4 acc = {0.f, 0.f, 0.f, 0.f};
                acc = __builtin_amdgcn_mfma_f32_16x16x32_bf16(ah, bl[n], acc, 0, 0, 0);
                acc = __builtin_amdgcn_mfma_f32_16x16x32_bf16(al, bh[n], acc, 0, 0, 0);
                acc = __builtin_amdgcn_mfma_f32_16x16x32_bf16(ah, bh[n], acc, 0, 0, 0);
#pragma unroll
                for (int i = 0; i < 4; ++i) {
                    const float y = acc[i] + cbv[n];
                    if (MODE == 0) {
                        a0[n] += y;
                        a1[n] = fmaf(y, y, a1[n]);
                    } else {
                        a0[n] += fmaxf(fmaf(y, av[n], bvv[n]), 0.f);
                    }
                }
            }
        }
    }

    // ---- reduce: sum the 4 row-groups (lanes l, l^16, l^32 cover same C column)
#pragma unroll
    for (int n = 0; n < 4; ++n) {
        a0[n] += __shfl_xor(a0[n], 16);
        a0[n] += __shfl_xor(a0[n], 32);
        if (MODE == 0) {
            a1[n] += __shfl_xor(a1[n], 16);
            a1[n] += __shfl_xor(a1[n], 32);
        }
    }
    __shared__ float red[4][4][16][2];
    if (lane < 16) {
#pragma unroll
        for (int n = 0; n < 4; ++n) {
            red[wv][n][lane][0] = a0[n];
            red[wv][n][lane][1] = (MODE == 0) ? a1[n] : 0.f;
        }
    }
    __syncthreads();
    if (t < 64) {
        const int n = t >> 4, m = t & 15;
        const float S = red[0][n][m][0] + red[1][n][m][0] + red[2][n][m][0] + red[3][n][m][0];
        if (MODE == 0) {
            const float Q = red[0][n][m][1] + red[1][n][m][1] + red[2][n][m][1] + red[3][n][m][1];
            atomicAdd(&ws[OFF_CHSUM + t], S);
            atomicAdd(&ws[OFF_CHSQ + t], Q);
        } else {
            atomicAdd(&ws[OFF_FEAT + b * 64 + t], S);
        }
    }
}

// ---------------- tail kernels ----------------

__global__ void k_stats(const float* __restrict__ bn_w, const float* __restrict__ bn_b,
                        float* __restrict__ ws) {
    int c = threadIdx.x;
    if (c < 64) {
        const float invN = 1.f / (float)(BB * HH * WW);
        float mu  = ws[OFF_CHSUM + c] * invN;
        float var = ws[OFF_CHSQ + c] * invN - mu * mu;
        float rs  = rsqrtf(var + 1e-5f);
        float A   = rs * bn_w[c];
        ws[OFF_A + c] = A;
        ws[OFF_B + c] = bn_b[c] - mu * A;
    }
}

__global__ void k_volt(const float* __restrict__ fcw, const float* __restrict__ fcb,
                       float* __restrict__ ws) {
    __shared__ float sv[16 * 3];
    int t = threadIdx.x;
    if (t < 16) {
        const float inv = 1.f / 65536.f;
        float raw[5];
#pragma unroll
        for (int j = 0; j < 5; ++j) {
            float a = fcb[j];
            for (int c2 = 0; c2 < 64; ++c2)
                a = fmaf(fcw[j * 64 + c2], ws[OFF_FEAT + t * 64 + c2] * inv, a);
            raw[j] = a;
        }
#define CS(i, j)                              \
        {                                     \
            float lo = fminf(raw[i], raw[j]); \
            float hi = fmaxf(raw[i], raw[j]); \
            raw[i] = lo;                      \
            raw[j] = hi;                      \
        }
        CS(0, 1) CS(3, 4) CS(2, 4) CS(2, 3) CS(0, 3) CS(0, 2) CS(1, 4) CS(1, 3) CS(1, 2)
#undef CS
        float mn = raw[0], mx = raw[4];
        float s = 10.f / (mx - mn + 1e-8f);
        sv[t * 3 + 0] = (raw[1] - mn) * s;
        sv[t * 3 + 1] = (raw[2] - mn) * s;
        sv[t * 3 + 2] = (raw[3] - mn) * s;
    }
    __syncthreads();
    for (int i = t; i < SRF_N; i += 256) {
        int b = i / 93, rr = i % 93, c2 = rr / 31, a = rr % 31;
        float band = 400.f + (300.f * (float)a) / 31.f;
        float v = sv[b * 3 + c2];
        float sh = sinf(0.031415926535897934f / v);
        ws[OFF_SRF + i] = (sh * sh) / (band * 1e-6f);
    }
}

__global__ __launch_bounds__(256) void k_apply(const float* __restrict__ xh,
                                               const float* __restrict__ ws,
                                               float* __restrict__ out) {
    __shared__ float4 s_srf[31];
    __shared__ float s_x[256 * 31];
    __shared__ float s_o[256 * 3];
    int t = threadIdx.x;
    int blk = blockIdx.x;
    int b = blk >> 8;
    size_t pix0 = (size_t)blk << 8;

    if (t < 124) {
        int a = t >> 2, c2 = t & 3;
        ((float*)s_srf)[t] = (c2 < 3) ? ws[OFF_SRF + b * 93 + c2 * 31 + a] : 0.f;
    }
    const float4* xg = (const float4*)(xh + pix0 * 31);
    float4* sx4 = (float4*)s_x;
#pragma unroll
    for (int i = 0; i < 8; ++i) {
        int idx = t + (i << 8);
        if (idx < 1984) sx4[idx] = xg[idx];
    }
    __syncthreads();

    float a0 = 0.f, a1 = 0.f, a2 = 0.f;
    const float* px = s_x + t * 31;
#pragma unroll
    for (int a = 0; a < 31; ++a) {
        float v = px[a];
        float4 s = s_srf[a];
        a0 = fmaf(v, s.x, a0);
        a1 = fmaf(v, s.y, a1);
        a2 = fmaf(v, s.z, a2);
    }
    s_o[t * 3 + 0] = a0;
    s_o[t * 3 + 1] = a1;
    s_o[t * 3 + 2] = a2;
    __syncthreads();
    float* ob = out + pix0 * 3;
#pragma unroll
    for (int i = 0; i < 3; ++i) ob[t + (i << 8)] = s_o[t + (i << 8)];
}

extern "C" void kernel_launch(void* const* d_in, const int* in_sizes, int n_in,
                              void* d_out, int out_size, void* d_ws, size_t ws_size,
                              hipStream_t stream) {
    const float* x    = (const float*)d_in[0];
    const float* xhsi = (const float*)d_in[1];
    const float* cw   = (const float*)d_in[2];
    const float* cb   = (const float*)d_in[3];
    const float* bnw  = (const float*)d_in[4];
    const float* bnb  = (const float*)d_in[5];
    const float* fcw  = (const float*)d_in[6];
    const float* fcb  = (const float*)d_in[7];
    float* out = (float*)d_out;
    float* ws  = (float*)d_ws;

    hipLaunchKernelGGL(k_init, dim3(5), dim3(256), 0, stream, ws);
    hipLaunchKernelGGL((k_convm<0>), dim3(64, 16), dim3(256), 0, stream, x, cw, cb, ws);
    hipLaunchKernelGGL(k_stats, dim3(1), dim3(64), 0, stream, bnw, bnb, ws);
    hipLaunchKernelGGL((k_convm<1>), dim3(64, 16), dim3(256), 0, stream, x, cw, cb, ws);
    hipLaunchKernelGGL(k_volt, dim3(1), dim3(256), 0, stream, fcw, fcb, ws);
    hipLaunchKernelGGL(k_apply, dim3(4096), dim3(256), 0, stream, xhsi, ws, out);
}

// Round 7
// 104.453 us; speedup vs baseline: 2.4651x; 1.3440x over previous
//
#include <hip/hip_runtime.h>
#include <hip/hip_bf16.h>
#include <math.h>

#define BB 16
#define HH 256
#define WW 256

// ws layout in floats
#define OFF_CHSUM 0      // [64]
#define OFF_CHSQ  64     // [64]
#define OFF_A     128    // [64]  rsig * bn_w
#define OFF_B     192    // [64]  bn_b - mu * A
#define OFF_FEAT  256    // [16*64] pooled relu sums (pre-division)
#define OFF_SRF   1280   // [16*3*31]
#define SRF_N     (16 * 93)

typedef __attribute__((ext_vector_type(8))) short bf16x8;
typedef __attribute__((ext_vector_type(4))) float f32x4;

union BFu { __hip_bfloat16 h; short s; };
union ABu { bf16x8 v; unsigned u[4]; };

__device__ __forceinline__ short bf_hi(float v, float& resid) {
    BFu u; u.h = __float2bfloat16(v);
    resid = v - __bfloat162float(u.h);
    return u.s;
}
__device__ __forceinline__ short bf_of(float v) {
    BFu u; u.h = __float2bfloat16(v);
    return u.s;
}

__global__ void k_init(float* __restrict__ ws) {
    int i = blockIdx.x * 256 + threadIdx.x;
    if (i < 1280) ws[i] = 0.f;
}

// Implicit-GEMM conv, A-fragments gathered from a pre-split bf16(hi|lo) LDS panel.
// Block: 4 waves = image rows r0..r0+3, full 256-col width of one image.
// pan32[l][j]: row l <-> global row r0-1+l (l=0..5); dword j <-> input float gcf=j-3,
// packed (hi_bf16 | lo_bf16<<16). Row 6 = "ones" row: pack(1.0,0) everywhere,
// feeding A=1.0 at k=27 (bias column; B[27]=cb) and harmless k>=28 slots (B=0).
// Per 16-px m-tile: lane supplies A[px=16cs+(l&15)][k=(l>>4)*8+e] via 8 ds_read_b32.
// y = Ah*Bh + Ah*Bl + Al*Bh (split-bf16, ~1.5e-5 rel err; verified r6).
// MODE 0: per-channel sum/sumsq.  MODE 1: BN+ReLU, per-(b,c) pooled sum.
template <int MODE>
__global__ __launch_bounds__(256) void k_convg(const float* __restrict__ x,
                                               const float* __restrict__ cw,
                                               const float* __restrict__ cb,
                                               float* __restrict__ ws) {
    __shared__ unsigned pan32[7 * 776];
    __shared__ float red[4][4][16][2];
    const int t    = threadIdx.x;
    const int lane = t & 63;
    const int wv   = t >> 6;
    const int b    = blockIdx.y;
    const int r0   = blockIdx.x * 4;
    const int mrow = lane & 15;
    const int s    = lane >> 4;

    // ---- stage 6 rows (border-predicated, coalesced) with bf16 hi/lo split
    {
        const float* __restrict__ xb = x + (size_t)b * (HH * WW * 3);
        for (int e = t; e < 6 * 774; e += 256) {
            const int l = e / 774, j = e - l * 774;
            const int gr = r0 - 1 + l, gcf = j - 3;
            const bool ok = ((unsigned)gr < 256u) && ((unsigned)gcf < 768u);
            int off = gr * 768 + gcf;
            off = ok ? off : 0;
            float v = xb[off];
            v = ok ? v : 0.f;
            float rs2;
            const unsigned hi = (unsigned short)bf_hi(v, rs2);
            const unsigned lo = (unsigned short)bf_of(rs2);
            pan32[l * 776 + j] = hi | (lo << 16);
        }
        for (int j = t; j < 774; j += 256) pan32[6 * 776 + j] = 0x3F80u;  // pack(1.0, 0)
    }

    // ---- B fragments (weights, k-permuted; k=27 = bias) + BN consts
    bf16x8 bh[4], bl[4];
    float av[4], bvv[4];
#pragma unroll
    for (int n = 0; n < 4; ++n) {
        const int ch = n * 16 + mrow;
        if (MODE == 1) { av[n] = ws[OFF_A + ch]; bvv[n] = ws[OFF_B + ch]; }
        else { av[n] = 0.f; bvv[n] = 0.f; }
#pragma unroll
        for (int e = 0; e < 8; ++e) {
            const int k = s * 8 + e;
            float w = 0.f;
            if (k < 27) {
                const int kh = (k >= 18) ? 2 : (k >= 9 ? 1 : 0);
                const int j  = k - kh * 9;
                const int kw2 = j / 3, ci = j - kw2 * 3;
                w = cw[ch * 27 + ci * 9 + kh * 3 + kw2];
            } else if (k == 27) {
                w = cb[ch];
            }
            float rs2;
            bh[n][e] = bf_hi(w, rs2);
            bl[n][e] = bf_of(rs2);
        }
    }

    // ---- per-lane gather offsets (dword units), computed once
    int off8[8];
#pragma unroll
    for (int e = 0; e < 8; ++e) {
        const int k = s * 8 + e;
        if (k < 27) {
            const int kh = (k >= 18) ? 2 : (k >= 9 ? 1 : 0);
            off8[e] = (wv + kh) * 776 + (k - kh * 9);
        } else {
            off8[e] = 6 * 776 + (e - 3);   // ones row (k=27 -> bias; k>=28 -> B=0)
        }
    }

    __syncthreads();

    float a0[4] = {0.f, 0.f, 0.f, 0.f};
    float a1[4] = {0.f, 0.f, 0.f, 0.f};

#define GATHER(W, CS)                                                  \
    {                                                                  \
        const int c3 = ((CS) * 16 + mrow) * 3;                         \
        W[0] = pan32[off8[0] + c3]; W[1] = pan32[off8[1] + c3];        \
        W[2] = pan32[off8[2] + c3]; W[3] = pan32[off8[3] + c3];        \
        W[4] = pan32[off8[4] + c3]; W[5] = pan32[off8[5] + c3];        \
        W[6] = pan32[off8[6] + c3]; W[7] = pan32[off8[7] + c3];        \
    }
#define COMPUTE(W)                                                     \
    {                                                                  \
        ABu ua, ul;                                                    \
        ua.u[0] = (W[0] & 0xFFFFu) | (W[1] << 16);                     \
        ua.u[1] = (W[2] & 0xFFFFu) | (W[3] << 16);                     \
        ua.u[2] = (W[4] & 0xFFFFu) | (W[5] << 16);                     \
        ua.u[3] = (W[6] & 0xFFFFu) | (W[7] << 16);                     \
        ul.u[0] = (W[0] >> 16) | (W[1] & 0xFFFF0000u);                 \
        ul.u[1] = (W[2] >> 16) | (W[3] & 0xFFFF0000u);                 \
        ul.u[2] = (W[4] >> 16) | (W[5] & 0xFFFF0000u);                 \
        ul.u[3] = (W[6] >> 16) | (W[7] & 0xFFFF0000u);                 \
        const bf16x8 ah = ua.v, al = ul.v;                             \
        _Pragma("unroll")                                              \
        for (int n = 0; n < 4; ++n) {                                  \
            f32x4 acc = {0.f, 0.f, 0.f, 0.f};                          \
            acc = __builtin_amdgcn_mfma_f32_16x16x32_bf16(ah, bl[n], acc, 0, 0, 0); \
            acc = __builtin_amdgcn_mfma_f32_16x16x32_bf16(al, bh[n], acc, 0, 0, 0); \
            acc = __builtin_amdgcn_mfma_f32_16x16x32_bf16(ah, bh[n], acc, 0, 0, 0); \
            _Pragma("unroll")                                          \
            for (int i = 0; i < 4; ++i) {                              \
                const float y = acc[i];                                \
                if (MODE == 0) { a0[n] += y; a1[n] = fmaf(y, y, a1[n]); } \
                else { a0[n] += fmaxf(fmaf(y, av[n], bvv[n]), 0.f); }  \
            }                                                          \
        }                                                              \
    }

    unsigned Wa[8], Wb[8];
    GATHER(Wa, 0)
    GATHER(Wb, 1)  COMPUTE(Wa)
    GATHER(Wa, 2)  COMPUTE(Wb)
    GATHER(Wb, 3)  COMPUTE(Wa)
    GATHER(Wa, 4)  COMPUTE(Wb)
    GATHER(Wb, 5)  COMPUTE(Wa)
    GATHER(Wa, 6)  COMPUTE(Wb)
    GATHER(Wb, 7)  COMPUTE(Wa)
    GATHER(Wa, 8)  COMPUTE(Wb)
    GATHER(Wb, 9)  COMPUTE(Wa)
    GATHER(Wa, 10) COMPUTE(Wb)
    GATHER(Wb, 11) COMPUTE(Wa)
    GATHER(Wa, 12) COMPUTE(Wb)
    GATHER(Wb, 13) COMPUTE(Wa)
    GATHER(Wa, 14) COMPUTE(Wb)
    GATHER(Wb, 15) COMPUTE(Wa)
    COMPUTE(Wb)
#undef GATHER
#undef COMPUTE

    // ---- reduce over px (rows of C): lanes l, l^16, l^32 share a C column
#pragma unroll
    for (int n = 0; n < 4; ++n) {
        a0[n] += __shfl_xor(a0[n], 16);
        a0[n] += __shfl_xor(a0[n], 32);
        if (MODE == 0) {
            a1[n] += __shfl_xor(a1[n], 16);
            a1[n] += __shfl_xor(a1[n], 32);
        }
    }
    if (lane < 16) {
#pragma unroll
        for (int n = 0; n < 4; ++n) {
            red[wv][n][lane][0] = a0[n];
            red[wv][n][lane][1] = (MODE == 0) ? a1[n] : 0.f;
        }
    }
    __syncthreads();
    if (t < 64) {
        const int n = t >> 4, m = t & 15;
        const float S = red[0][n][m][0] + red[1][n][m][0] + red[2][n][m][0] + red[3][n][m][0];
        if (MODE == 0) {
            const float Q = red[0][n][m][1] + red[1][n][m][1] + red[2][n][m][1] + red[3][n][m][1];
            atomicAdd(&ws[OFF_CHSUM + t], S);
            atomicAdd(&ws[OFF_CHSQ + t], Q);
        } else {
            atomicAdd(&ws[OFF_FEAT + b * 64 + t], S);
        }
    }
}

// ---------------- tail kernels ----------------

__global__ void k_stats(const float* __restrict__ bn_w, const float* __restrict__ bn_b,
                        float* __restrict__ ws) {
    int c = threadIdx.x;
    if (c < 64) {
        const float invN = 1.f / (float)(BB * HH * WW);
        float mu  = ws[OFF_CHSUM + c] * invN;
        float var = ws[OFF_CHSQ + c] * invN - mu * mu;
        float rs  = rsqrtf(var + 1e-5f);
        float A   = rs * bn_w[c];
        ws[OFF_A + c] = A;
        ws[OFF_B + c] = bn_b[c] - mu * A;
    }
}

__global__ void k_volt(const float* __restrict__ fcw, const float* __restrict__ fcb,
                       float* __restrict__ ws) {
    __shared__ float sv[16 * 3];
    int t = threadIdx.x;
    if (t < 16) {
        const float inv = 1.f / 65536.f;
        float raw[5];
#pragma unroll
        for (int j = 0; j < 5; ++j) {
            float a = fcb[j];
            for (int c2 = 0; c2 < 64; ++c2)
                a = fmaf(fcw[j * 64 + c2], ws[OFF_FEAT + t * 64 + c2] * inv, a);
            raw[j] = a;
        }
#define CS(i, j)                              \
        {                                     \
            float lo = fminf(raw[i], raw[j]); \
            float hi = fmaxf(raw[i], raw[j]); \
            raw[i] = lo;                      \
            raw[j] = hi;                      \
        }
        CS(0, 1) CS(3, 4) CS(2, 4) CS(2, 3) CS(0, 3) CS(0, 2) CS(1, 4) CS(1, 3) CS(1, 2)
#undef CS
        float mn = raw[0], mx = raw[4];
        float s = 10.f / (mx - mn + 1e-8f);
        sv[t * 3 + 0] = (raw[1] - mn) * s;
        sv[t * 3 + 1] = (raw[2] - mn) * s;
        sv[t * 3 + 2] = (raw[3] - mn) * s;
    }
    __syncthreads();
    for (int i = t; i < SRF_N; i += 256) {
        int b = i / 93, rr = i % 93, c2 = rr / 31, a = rr % 31;
        float band = 400.f + (300.f * (float)a) / 31.f;
        float v = sv[b * 3 + c2];
        float sh = sinf(0.031415926535897934f / v);
        ws[OFF_SRF + i] = (sh * sh) / (band * 1e-6f);
    }
}

__global__ __launch_bounds__(256) void k_apply(const float* __restrict__ xh,
                                               const float* __restrict__ ws,
                                               float* __restrict__ out) {
    __shared__ float4 s_srf[31];
    __shared__ float s_x[256 * 31];
    __shared__ float s_o[256 * 3];
    int t = threadIdx.x;
    int blk = blockIdx.x;
    int b = blk >> 8;
    size_t pix0 = (size_t)blk << 8;

    if (t < 124) {
        int a = t >> 2, c2 = t & 3;
        ((float*)s_srf)[t] = (c2 < 3) ? ws[OFF_SRF + b * 93 + c2 * 31 + a] : 0.f;
    }
    const float4* xg = (const float4*)(xh + pix0 * 31);
    float4* sx4 = (float4*)s_x;
#pragma unroll
    for (int i = 0; i < 8; ++i) {
        int idx = t + (i << 8);
        if (idx < 1984) sx4[idx] = xg[idx];
    }
    __syncthreads();

    float a0 = 0.f, a1 = 0.f, a2 = 0.f;
    const float* px = s_x + t * 31;
#pragma unroll
    for (int a = 0; a < 31; ++a) {
        float v = px[a];
        float4 s = s_srf[a];
        a0 = fmaf(v, s.x, a0);
        a1 = fmaf(v, s.y, a1);
        a2 = fmaf(v, s.z, a2);
    }
    s_o[t * 3 + 0] = a0;
    s_o[t * 3 + 1] = a1;
    s_o[t * 3 + 2] = a2;
    __syncthreads();
    float* ob = out + pix0 * 3;
#pragma unroll
    for (int i = 0; i < 3; ++i) ob[t + (i << 8)] = s_o[t + (i << 8)];
}

extern "C" void kernel_launch(void* const* d_in, const int* in_sizes, int n_in,
                              void* d_out, int out_size, void* d_ws, size_t ws_size,
                              hipStream_t stream) {
    const float* x    = (const float*)d_in[0];
    const float* xhsi = (const float*)d_in[1];
    const float* cw   = (const float*)d_in[2];
    const float* cb   = (const float*)d_in[3];
    const float* bnw  = (const float*)d_in[4];
    const float* bnb  = (const float*)d_in[5];
    const float* fcw  = (const float*)d_in[6];
    const float* fcb  = (const float*)d_in[7];
    float* out = (float*)d_out;
    float* ws  = (float*)d_ws;

    hipLaunchKernelGGL(k_init, dim3(5), dim3(256), 0, stream, ws);
    hipLaunchKernelGGL((k_convg<0>), dim3(64, 16), dim3(256), 0, stream, x, cw, cb, ws);
    hipLaunchKernelGGL(k_stats, dim3(1), dim3(64), 0, stream, bnw, bnb, ws);
    hipLaunchKernelGGL((k_convg<1>), dim3(64, 16), dim3(256), 0, stream, x, cw, cb, ws);
    hipLaunchKernelGGL(k_volt, dim3(1), dim3(256), 0, stream, fcw, fcb, ws);
    hipLaunchKernelGGL(k_apply, dim3(4096), dim3(256), 0, stream, xhsi, ws, out);
}